// Round 19
// baseline (187.199 us; speedup 1.0000x reference)
//
#include <hip/hip_runtime.h>
#include <hip/hip_bf16.h>
#include <stdint.h>

typedef __bf16 bf16_t;
typedef __bf16 bf16x8 __attribute__((ext_vector_type(8)));
typedef float f32x4 __attribute__((ext_vector_type(4)));
typedef float f32x16 __attribute__((ext_vector_type(16)));
typedef unsigned uint2e __attribute__((ext_vector_type(2)));

#define SEQ_LEN 4096
#define D_MODEL 1024
#define N_HEAD 16

// Fragment-layout buffers (per head = 128 tiles x 2048 elems = 512KB):
//   QF[h][t][ks][hi][l31][e]  =      Q[t*32+l31][h*64 + ks*16 + hi*8 + e]
//   KF[h][t][ks][hi][l31][e]  = sc * K[t*32+l31][h*64 + ks*16 + hi*8 + e]
//   VF[h][t][dt][g2][hi][l31][e] = V[t*32 + g2*16 + hi*8 + e][h*64 + dt*32 + l31]

// ---------- helpers ----------

__device__ __forceinline__ void gload_lds16(const void* g, void* lds) {
  __builtin_amdgcn_global_load_lds(
      (__attribute__((address_space(1))) void*)(g),
      (__attribute__((address_space(3))) void*)(lds), 16, 0, 0);
}

__device__ __forceinline__ unsigned short f2bfu(float f) {
  __bf16 h = (__bf16)f;
  return __builtin_bit_cast(unsigned short, h);
}

__device__ __forceinline__ unsigned cvt_pk_bf16(float a, float b) {
  unsigned r;
  asm("v_cvt_pk_bf16_f32 %0, %1, %2" : "=v"(r) : "v"(a), "v"(b));
  return r;  // lo = bf16(a), hi = bf16(b)
}

#define CBAR() asm volatile("" ::: "memory")

// ---------- fused prep: x->bf16 cvt + both weight transposes, ONE launch ----

__global__ __launch_bounds__(256) void prep_fused(const float* __restrict__ x,
                                                  bf16_t* __restrict__ xh,
                                                  const float* __restrict__ w_qkv,
                                                  bf16_t* __restrict__ wqkvT,
                                                  const float* __restrict__ w_o,
                                                  bf16_t* __restrict__ woT) {
  __shared__ float tile[64][65];
  const int b = blockIdx.x;
  if (b < 4096) {
    int i = (b * 256 + threadIdx.x) * 4;
    float4 v = *(const float4*)(x + i);
    unsigned int lo = (unsigned)f2bfu(v.x) | ((unsigned)f2bfu(v.y) << 16);
    unsigned int hi = (unsigned)f2bfu(v.z) | ((unsigned)f2bfu(v.w) << 16);
    uint2 pk; pk.x = lo; pk.y = hi;
    *(uint2*)(xh + i) = pk;
    return;
  }
  const float* W;
  bf16_t* Wt;
  int C, bi;
  if (b < 4864) { W = w_qkv; Wt = wqkvT; C = 3072; bi = b - 4096; }
  else          { W = w_o;   Wt = woT;   C = 1024; bi = b - 4864; }
  const int R = 1024;
  const int tc = C >> 6;
  const int bc = bi % tc;
  const int br = bi / tc;
  #pragma unroll
  for (int p = 0; p < 16; ++p) {
    int idx = p * 256 + threadIdx.x;
    int i = idx >> 6, j = idx & 63;
    tile[i][j] = W[(size_t)(br * 64 + i) * C + bc * 64 + j];
  }
  __syncthreads();
  #pragma unroll
  for (int p = 0; p < 16; ++p) {
    int idx = p * 256 + threadIdx.x;
    int jj = idx >> 6, ii = idx & 63;
    Wt[(size_t)(bc * 64 + jj) * R + br * 64 + ii] = (bf16_t)tile[ii][jj];
  }
}

// ---------- GEMM1: 256x256 tile, BK=64, 8-phase counted-vmcnt schedule ------

__device__ __forceinline__ void stage_half(const bf16_t* src, char* ldsbase,
                                           int w, int srow, int schunk) {
  const bf16_t* s0 = src + (size_t)(w * 8 + srow) * 1024 + schunk * 8;
  char* d0 = ldsbase + w * 1024;
  gload_lds16(s0, d0);
  gload_lds16(s0 + 64 * 1024, d0 + 8192);
}

__global__ __launch_bounds__(512, 2) void gemm1_8p(const bf16_t* __restrict__ A,
                                                   const bf16_t* __restrict__ Bt,
                                                   const float* __restrict__ bias,
                                                   bf16_t* __restrict__ qfout,
                                                   bf16_t* __restrict__ kfout,
                                                   bf16_t* __restrict__ vfout) {
  __shared__ char ldsbuf[131072];
  const int tid = threadIdx.x;
  const int lane = tid & 63;
  const int w = tid >> 6;
  const int wm = w >> 2;
  const int wn = w & 3;
  const int i16 = lane & 15;
  const int g = lane >> 4;
  const int hi = lane >> 5;
  const int bswz = (blockIdx.x & 7) * 24 + (blockIdx.x >> 3);
  const int bm = bswz / 12;
  const int bn = bswz % 12;

  const int srow = lane >> 3;
  const int schunk = (lane & 7) ^ (hi << 1);
  const int s5 = ((i16 >> 2) & 1) << 5;

  auto stA = [&](int buf, int half, int kt) {
    stage_half(A + (size_t)(bm * 256 + half * 128) * 1024 + kt * 64,
               ldsbuf + buf * 32768 + half * 16384, w, srow, schunk);
  };
  auto stB = [&](int buf, int half, int kt) {
    stage_half(Bt + (size_t)(bn * 256 + half * 128) * 1024 + kt * 64,
               ldsbuf + 65536 + buf * 32768 + half * 16384, w, srow, schunk);
  };

  f32x4 acc[8][4];
  #pragma unroll
  for (int m = 0; m < 8; ++m)
    #pragma unroll
    for (int n = 0; n < 4; ++n)
      acc[m][n] = (f32x4){0.f, 0.f, 0.f, 0.f};

  const int browbase = (wn & 1) * 64;

  stA(0, 0, 0); stA(0, 1, 0); stB(0, 0, 0); stB(0, 1, 0);
  stB(1, 0, 1); stB(1, 1, 1);
  asm volatile("s_waitcnt vmcnt(4)" ::: "memory");
  CBAR(); __builtin_amdgcn_s_barrier(); CBAR();

  bf16x8 bfr[4][2];

  for (int i = 0; i < 8; ++i) {
    const int t1 = 2 * i + 1, t2 = 2 * i + 2, t3 = 2 * i + 3;
    #pragma unroll
    for (int p = 0; p < 8; ++p) {
      const int buf = p >> 2;
      const int q = p & 3;
      const char* aB = ldsbuf + buf * 32768 + wm * 16384;
      const char* bB = ldsbuf + 65536 + buf * 32768 + (wn >> 1) * 16384;
      if (q == 0) {
        #pragma unroll
        for (int n = 0; n < 4; ++n)
          #pragma unroll
          for (int ks = 0; ks < 2; ++ks) {
            int U = (browbase + n * 16 + i16) * 128 + ks * 64 + g * 16;
            bfr[n][ks] = *(const bf16x8*)(bB + (U ^ s5));
          }
      }
      bf16x8 af[2][2];
      #pragma unroll
      for (int mm = 0; mm < 2; ++mm)
        #pragma unroll
        for (int ks = 0; ks < 2; ++ks) {
          int U = ((q * 2 + mm) * 16 + i16) * 128 + ks * 64 + g * 16;
          af[mm][ks] = *(const bf16x8*)(aB + (U ^ s5));
        }
      if (p == 0)      stA(1, 0, t1);
      else if (p == 1) stA(1, 1, t1);
      else if (p == 2) { if (t2 < 16) stB(0, 0, t2); }
      else if (p == 3) { if (t2 < 16) stB(0, 1, t2); }
      else if (p == 4) { if (t2 < 16) stA(0, 0, t2); }
      else if (p == 5) { if (t2 < 16) stA(0, 1, t2); }
      else if (p == 6) { if (t3 < 16) stB(1, 0, t3); }
      else             { if (t3 < 16) stB(1, 1, t3); }

      CBAR(); __builtin_amdgcn_s_barrier(); CBAR();

      __builtin_amdgcn_s_setprio(1);
      #pragma unroll
      for (int mm = 0; mm < 2; ++mm)
        #pragma unroll
        for (int n = 0; n < 4; ++n)
          #pragma unroll
          for (int ks = 0; ks < 2; ++ks)
            acc[q * 2 + mm][n] = __builtin_amdgcn_mfma_f32_16x16x32_bf16(
                af[mm][ks], bfr[n][ks], acc[q * 2 + mm][n], 0, 0, 0);
      __builtin_amdgcn_s_setprio(0);

      if (p == 3) {
        if (i == 7) asm volatile("s_waitcnt vmcnt(0)" ::: "memory");
        else        asm volatile("s_waitcnt vmcnt(4)" ::: "memory");
      } else if (p == 7 && i < 7) {
        asm volatile("s_waitcnt vmcnt(4)" ::: "memory");
      }
      CBAR(); __builtin_amdgcn_s_barrier(); CBAR();
    }
  }

  #pragma unroll
  for (int m = 0; m < 8; ++m) {
    #pragma unroll
    for (int n = 0; n < 4; ++n) {
      int col = bn * 256 + wn * 64 + n * 16 + i16;
      float bv = bias[col];
      int row0 = bm * 256 + wm * 128 + m * 16 + g * 4;
      if (col < 2048) {
        const bool isK = (col >= 1024);
        const float scl = isK ? 0.18033688011112042f : 1.0f;
        bf16_t* base = isK ? kfout : qfout;
        int dg = col & 1023;
        int hh = dg >> 6, d = dg & 63;
        int ks = d >> 4, hib = (d >> 3) & 1, e = d & 7;
        int t = row0 >> 5, l0 = row0 & 31;
        bf16_t* fp = base + (size_t)hh * 262144 + t * 2048 + ks * 512 +
                     hib * 256 + l0 * 8 + e;
        #pragma unroll
        for (int r = 0; r < 4; ++r)
          fp[r * 8] = (bf16_t)((acc[m][n][r] + bv) * scl);
      } else {
        int dg = col - 2048;
        int hh = dg >> 6, dh = dg & 63;
        int dt = dh >> 5, l31v = dh & 31;
        int t = row0 >> 5, inner = row0 & 31;
        int g2 = inner >> 4, hiv = (inner >> 3) & 1, e0 = inner & 7;
        uint2 pk;
        pk.x = cvt_pk_bf16(acc[m][n][0] + bv, acc[m][n][1] + bv);
        pk.y = cvt_pk_bf16(acc[m][n][2] + bv, acc[m][n][3] + bv);
        *(uint2*)(vfout + (size_t)hh * 262144 + t * 2048 + dt * 1024 +
                  g2 * 512 + hiv * 256 + l31v * 8 + e0) = pk;
      }
    }
  }
}

// ---------- GEMM2 (128^2 m97 structure): C = A * Bt^T + bias, fp32 out -----

__global__ __launch_bounds__(256) void gemm_bt(const bf16_t* __restrict__ A,
                                               const bf16_t* __restrict__ Bt,
                                               const float* __restrict__ bias,
                                               float* __restrict__ Cout,
                                               int M, int N, int K) {
  __shared__ bf16_t As[128 * 32];
  __shared__ bf16_t Bs[128 * 32];
  const int tid = threadIdx.x;
  const int lane = tid & 63;
  const int w = tid >> 6;
  const int wr = (w >> 1) * 64;
  const int wc = (w & 1) * 64;
  const int i16 = lane & 15;
  const int g = lane >> 4;
  const int ntn = N >> 7;
  const int nwg = gridDim.x;
  const int bswz = (blockIdx.x & 7) * (nwg >> 3) + (blockIdx.x >> 3);
  const int bm = bswz / ntn;
  const int bn = bswz % ntn;
  const bf16_t* Abase = A + (size_t)(bm * 128) * K;
  const bf16_t* Bbase = Bt + (size_t)(bn * 128) * K;

  f32x4 acc[4][4];
  #pragma unroll
  for (int m = 0; m < 4; ++m)
    #pragma unroll
    for (int n = 0; n < 4; ++n)
      acc[m][n] = (f32x4){0.f, 0.f, 0.f, 0.f};

  for (int kt = 0; kt < K; kt += 32) {
    __syncthreads();
    #pragma unroll
    for (int p = 0; p < 2; ++p) {
      int idx = p * 256 + tid;
      int row = idx >> 2, ch = idx & 3;
      gload_lds16(Abase + (size_t)row * K + kt + ch * 8, (char*)As + idx * 16);
      gload_lds16(Bbase + (size_t)row * K + kt + ch * 8, (char*)Bs + idx * 16);
    }
    __syncthreads();
    bf16x8 af[4], bq[4];
    #pragma unroll
    for (int m = 0; m < 4; ++m)
      af[m] = *(const bf16x8*)(As + (wr + m * 16 + i16) * 32 + g * 8);
    #pragma unroll
    for (int n = 0; n < 4; ++n)
      bq[n] = *(const bf16x8*)(Bs + (wc + n * 16 + i16) * 32 + g * 8);
    #pragma unroll
    for (int m = 0; m < 4; ++m)
      #pragma unroll
      for (int n = 0; n < 4; ++n)
        acc[m][n] = __builtin_amdgcn_mfma_f32_16x16x32_bf16(af[m], bq[n], acc[m][n], 0, 0, 0);
  }

  #pragma unroll
  for (int m = 0; m < 4; ++m) {
    #pragma unroll
    for (int n = 0; n < 4; ++n) {
      int col = bn * 128 + wc + n * 16 + i16;
      float bv = bias ? bias[col] : 0.f;
      int row0 = bm * 128 + wr + m * 16 + g * 4;
      #pragma unroll
      for (int r = 0; r < 4; ++r)
        Cout[(size_t)(row0 + r) * N + col] = acc[m][n][r] + bv;
    }
  }
}

// ---------- causal flash attention v3: LDS-shared K/V, 4x L2-traffic cut ----
// Block = (head, 128 q-rows), 4 waves each OWN 32 distinct q-rows (no
// KV-split, no merge). Each K/V tile (4KB contiguous in fragment layout) is
// staged ONCE per block into double-buffered LDS via one gload_lds per
// buffer (linear both sides); each wave ds_read_b128's its fragments
// (conflict-free: lanes 0-7 span all 32 banks). One barrier per tile; its
// implicit vmcnt drain lands the prefetch. Waves idle past their causal
// limit. L2 read traffic: 2.11GB -> 541MB (was at the 35TB/s L2 ceiling).
// Per-tile math identical to round 18 (scale-folded exp2, permlane pack).
// S^T = mfma_32x32(K', Q): lane q = lane&31, keys (r&3)+8*(r>>2)+4*(lane>>5).
// O^T = mfma_32x32(V^T, P^T). P = exp2(S') shift-free.

__global__ __launch_bounds__(256) void attn_fwd(const bf16_t* __restrict__ qf_,
                                                const bf16_t* __restrict__ kf,
                                                const bf16_t* __restrict__ vf,
                                                bf16_t* __restrict__ aout) {
  __shared__ __align__(16) bf16_t Ks[2][2048];
  __shared__ __align__(16) bf16_t Vs[2][2048];
  const int tid = threadIdx.x;
  const int w = tid >> 6;
  const int lane = tid & 63;
  const int l31 = lane & 31;
  const int hi = lane >> 5;
  const int bid = blockIdx.x;
  const int h = ((bid & 7) << 1) | ((bid >> 3) & 1);  // 2 heads per XCD
  const int J = 31 - (bid >> 4);                      // heavy q-blocks first
  const int jw = 4 * J + w;                           // wave's last tile
  const int q = J * 128 + w * 32 + l31;               // lane's q row

  // Q B-frags from QF layout (wave's q-tile index = jw)
  const bf16_t* qp = qf_ + (size_t)h * 262144 + (size_t)jw * 2048 + hi * 256 + l31 * 8;
  bf16x8 qf[4];
  #pragma unroll
  for (int ks = 0; ks < 4; ++ks)
    qf[ks] = *(const bf16x8*)(qp + ks * 512);

  const bf16_t* kh = kf + (size_t)h * 262144;
  const bf16_t* vh = vf + (size_t)h * 262144;

  f32x16 ot0, ot1;
  #pragma unroll
  for (int r = 0; r < 16; ++r) { ot0[r] = 0.f; ot1[r] = 0.f; }
  float l_run = 0.f;

  const int ntb = 4 * J + 4;   // tiles this block must process
  const int lfb = lane >> 5;   // (unused beyond hi; kept minimal)
  (void)lfb;

  // stage tile 0 (all 4 waves cooperatively: 256 threads x 16B = 4KB each)
  gload_lds16(kh + tid * 8, (char*)Ks[0] + tid * 16);
  gload_lds16(vh + tid * 8, (char*)Vs[0] + tid * 16);
  __syncthreads();
  int cur = 0;

  for (int t = 0; t < ntb; ++t) {
    // prefetch next tile into the other buffer
    if (t + 1 < ntb) {
      gload_lds16(kh + (size_t)(t + 1) * 2048 + tid * 8, (char*)Ks[cur ^ 1] + tid * 16);
      gload_lds16(vh + (size_t)(t + 1) * 2048 + tid * 8, (char*)Vs[cur ^ 1] + tid * 16);
    }

    if (t <= jw) {
      const char* Kc = (const char*)Ks[cur];
      const char* Vc = (const char*)Vs[cur];

      // K fragments: byte off = ks*1024 + hi*512 + l31*16 (conflict-free b128)
      bf16x8 kfr[4];
      #pragma unroll
      for (int ks = 0; ks < 4; ++ks)
        kfr[ks] = *(const bf16x8*)(Kc + ks * 1024 + hi * 512 + l31 * 16);

      f32x16 s;
      #pragma unroll
      for (int r = 0; r < 16; ++r) s[r] = 0.f;
      __builtin_amdgcn_s_setprio(1);
      #pragma unroll
      for (int ks = 0; ks < 4; ++ks)
        s = __builtin_amdgcn_mfma_f32_32x32x16_bf16(kfr[ks], qf[ks], s, 0, 0, 0);
      __builtin_amdgcn_s_setprio(0);

      // causal mask on the wave's diagonal tile
      if (t == jw) {
        #pragma unroll
        for (int r = 0; r < 16; ++r) {
          int c = (r & 3) + 8 * (r >> 2) + 4 * hi;
          if (c > l31) s[r] = -1e30f;
        }
      }

      #pragma unroll
      for (int r = 0; r < 16; ++r)
        s[r] = __builtin_amdgcn_exp2f(s[r]);

      float sm[8];
      #pragma unroll
      for (int r = 0; r < 8; ++r) sm[r] = s[r] + s[r + 8];
      #pragma unroll
      for (int r = 0; r < 4; ++r) sm[r] = sm[r] + sm[r + 4];
      l_run += (sm[0] + sm[1]) + (sm[2] + sm[3]);

      // T12 pack: 8 cvt_pk + 4 permlane32_swap (both outputs), zero selects
      bf16x8 pb[2];
      #pragma unroll
      for (int g2 = 0; g2 < 2; ++g2) {
        const int r0 = g2 * 8;
        unsigned a0 = cvt_pk_bf16(s[r0 + 0], s[r0 + 1]);
        unsigned a1 = cvt_pk_bf16(s[r0 + 2], s[r0 + 3]);
        unsigned b0 = cvt_pk_bf16(s[r0 + 4], s[r0 + 5]);
        unsigned b1 = cvt_pk_bf16(s[r0 + 6], s[r0 + 7]);
        uint2e p0 = __builtin_amdgcn_permlane32_swap(a0, b0, false, false);
        uint2e p1 = __builtin_amdgcn_permlane32_swap(a1, b1, false, false);
        uint4 f;
        f.x = p0[0];
        f.y = p1[0];
        f.z = p0[1];
        f.w = p1[1];
        pb[g2] = __builtin_bit_cast(bf16x8, f);
      }

      // V fragments + PV: byte off = dt*2048 + g2*1024 + hi*512 + l31*16
      __builtin_amdgcn_s_setprio(1);
      {
        bf16x8 v0 = *(const bf16x8*)(Vc + 0 * 2048 + 0 * 1024 + hi * 512 + l31 * 16);
        bf16x8 v1 = *(const bf16x8*)(Vc + 0 * 2048 + 1 * 1024 + hi * 512 + l31 * 16);
        bf16x8 v2 = *(const bf16x8*)(Vc + 1 * 2048 + 0 * 1024 + hi * 512 + l31 * 16);
        bf16x8 v3 = *(const bf16x8*)(Vc + 1 * 2048 + 1 * 1024 + hi * 512 + l31 * 16);
        ot0 = __builtin_amdgcn_mfma_f32_32x32x16_bf16(v0, pb[0], ot0, 0, 0, 0);
        ot0 = __builtin_amdgcn_mfma_f32_32x32x16_bf16(v1, pb[1], ot0, 0, 0, 0);
        ot1 = __builtin_amdgcn_mfma_f32_32x32x16_bf16(v2, pb[0], ot1, 0, 0, 0);
        ot1 = __builtin_amdgcn_mfma_f32_32x32x16_bf16(v3, pb[1], ot1, 0, 0, 0);
      }
      __builtin_amdgcn_s_setprio(0);
    }

    __syncthreads();   // all waves done reading cur; prefetch drained
    cur ^= 1;
  }

  // epilogue: combine lane-half l sums once, write the wave's 32 q-rows
  float inv = 1.0f / (l_run + __shfl_xor(l_run, 32));
  #pragma unroll
  for (int dt = 0; dt < 2; ++dt) {
    const f32x16& o = dt ? ot1 : ot0;
    #pragma unroll
    for (int rq = 0; rq < 4; ++rq) {
      unsigned lo = cvt_pk_bf16(o[4 * rq + 0] * inv, o[4 * rq + 1] * inv);
      unsigned hi2 = cvt_pk_bf16(o[4 * rq + 2] * inv, o[4 * rq + 3] * inv);
      uint2 pk2; pk2.x = lo; pk2.y = hi2;
      *(uint2*)(aout + (size_t)q * 1024 + h * 64 + dt * 32 + 8 * rq + 4 * hi) = pk2;
    }
  }
}

// ---------- launch ----------

extern "C" void kernel_launch(void* const* d_in, const int* in_sizes, int n_in,
                              void* d_out, int out_size, void* d_ws, size_t ws_size,
                              hipStream_t stream) {
  const float* x     = (const float*)d_in[0];
  const float* w_qkv = (const float*)d_in[1];
  const float* b_qkv = (const float*)d_in[2];
  const float* w_o   = (const float*)d_in[3];
  const float* b_o   = (const float*)d_in[4];

  char* ws = (char*)d_ws;
  bf16_t* xh    = (bf16_t*)(ws);                          //  8 MiB
  bf16_t* wqkvT = (bf16_t*)(ws + 8388608);                //  6 MiB
  bf16_t* woT   = (bf16_t*)(ws + 14680064);               //  2 MiB
  bf16_t* qfb   = (bf16_t*)(ws + 16777216);               //  8 MiB  QF fragment layout
  bf16_t* kfb   = (bf16_t*)(ws + 25165824);               //  8 MiB  KF fragment layout
  bf16_t* vfb   = (bf16_t*)(ws + 33554432);               //  8 MiB  VF fragment layout
  bf16_t* aout  = (bf16_t*)(ws + 41943040);               //  8 MiB

  prep_fused<<<5120, 256, 0, stream>>>(x, xh, w_qkv, wqkvT, w_o, woT);

  gemm1_8p<<<192, 512, 0, stream>>>(xh, wqkvT, b_qkv, qfb, kfb, vfb);

  attn_fwd<<<N_HEAD * (SEQ_LEN / 128), 256, 0, stream>>>(qfb, kfb, vfb, aout);

  gemm_bt<<<(4096 / 128) * (1024 / 128), 256, 0, stream>>>(
      aout, woT, b_o, (float*)d_out, 4096, 1024, 1024);
}

// Round 20
// 130.426 us; speedup vs baseline: 1.4353x; 1.4353x over previous
//
#include <hip/hip_runtime.h>
#include <hip/hip_bf16.h>
#include <stdint.h>

typedef __bf16 bf16_t;
typedef __bf16 bf16x8 __attribute__((ext_vector_type(8)));
typedef float f32x4 __attribute__((ext_vector_type(4)));
typedef float f32x16 __attribute__((ext_vector_type(16)));
typedef unsigned uint2e __attribute__((ext_vector_type(2)));

#define SEQ_LEN 4096
#define D_MODEL 1024
#define N_HEAD 16

// Fragment-layout buffers (per head = 128 tiles x 2048 elems = 512KB):
//   QF[h][t][ks][hi][l31][e]  =      Q[t*32+l31][h*64 + ks*16 + hi*8 + e]
//   KF[h][t][ks][hi][l31][e]  = sc * K[t*32+l31][h*64 + ks*16 + hi*8 + e]
//   VF[h][t][dt][g2][hi][l31][e] = V[t*32 + g2*16 + hi*8 + e][h*64 + dt*32 + l31]

// ---------- helpers ----------

__device__ __forceinline__ void gload_lds16(const void* g, void* lds) {
  __builtin_amdgcn_global_load_lds(
      (__attribute__((address_space(1))) void*)(g),
      (__attribute__((address_space(3))) void*)(lds), 16, 0, 0);
}

__device__ __forceinline__ unsigned short f2bfu(float f) {
  __bf16 h = (__bf16)f;
  return __builtin_bit_cast(unsigned short, h);
}

__device__ __forceinline__ unsigned cvt_pk_bf16(float a, float b) {
  unsigned r;
  asm("v_cvt_pk_bf16_f32 %0, %1, %2" : "=v"(r) : "v"(a), "v"(b));
  return r;  // lo = bf16(a), hi = bf16(b)
}

#define CBAR() asm volatile("" ::: "memory")

// ---------- fused prep: x->bf16 cvt + both weight transposes, ONE launch ----

__global__ __launch_bounds__(256) void prep_fused(const float* __restrict__ x,
                                                  bf16_t* __restrict__ xh,
                                                  const float* __restrict__ w_qkv,
                                                  bf16_t* __restrict__ wqkvT,
                                                  const float* __restrict__ w_o,
                                                  bf16_t* __restrict__ woT) {
  __shared__ float tile[64][65];
  const int b = blockIdx.x;
  if (b < 4096) {
    int i = (b * 256 + threadIdx.x) * 4;
    float4 v = *(const float4*)(x + i);
    unsigned int lo = (unsigned)f2bfu(v.x) | ((unsigned)f2bfu(v.y) << 16);
    unsigned int hi = (unsigned)f2bfu(v.z) | ((unsigned)f2bfu(v.w) << 16);
    uint2 pk; pk.x = lo; pk.y = hi;
    *(uint2*)(xh + i) = pk;
    return;
  }
  const float* W;
  bf16_t* Wt;
  int C, bi;
  if (b < 4864) { W = w_qkv; Wt = wqkvT; C = 3072; bi = b - 4096; }
  else          { W = w_o;   Wt = woT;   C = 1024; bi = b - 4864; }
  const int R = 1024;
  const int tc = C >> 6;
  const int bc = bi % tc;
  const int br = bi / tc;
  #pragma unroll
  for (int p = 0; p < 16; ++p) {
    int idx = p * 256 + threadIdx.x;
    int i = idx >> 6, j = idx & 63;
    tile[i][j] = W[(size_t)(br * 64 + i) * C + bc * 64 + j];
  }
  __syncthreads();
  #pragma unroll
  for (int p = 0; p < 16; ++p) {
    int idx = p * 256 + threadIdx.x;
    int jj = idx >> 6, ii = idx & 63;
    Wt[(size_t)(bc * 64 + jj) * R + br * 64 + ii] = (bf16_t)tile[ii][jj];
  }
}

// ---------- GEMM1: 256x256 tile, BK=64, 8-phase counted-vmcnt schedule ------

__device__ __forceinline__ void stage_half(const bf16_t* src, char* ldsbase,
                                           int w, int srow, int schunk) {
  const bf16_t* s0 = src + (size_t)(w * 8 + srow) * 1024 + schunk * 8;
  char* d0 = ldsbase + w * 1024;
  gload_lds16(s0, d0);
  gload_lds16(s0 + 64 * 1024, d0 + 8192);
}

__global__ __launch_bounds__(512, 2) void gemm1_8p(const bf16_t* __restrict__ A,
                                                   const bf16_t* __restrict__ Bt,
                                                   const float* __restrict__ bias,
                                                   bf16_t* __restrict__ qfout,
                                                   bf16_t* __restrict__ kfout,
                                                   bf16_t* __restrict__ vfout) {
  __shared__ char ldsbuf[131072];
  const int tid = threadIdx.x;
  const int lane = tid & 63;
  const int w = tid >> 6;
  const int wm = w >> 2;
  const int wn = w & 3;
  const int i16 = lane & 15;
  const int g = lane >> 4;
  const int hi = lane >> 5;
  const int bswz = (blockIdx.x & 7) * 24 + (blockIdx.x >> 3);
  const int bm = bswz / 12;
  const int bn = bswz % 12;

  const int srow = lane >> 3;
  const int schunk = (lane & 7) ^ (hi << 1);
  const int s5 = ((i16 >> 2) & 1) << 5;

  auto stA = [&](int buf, int half, int kt) {
    stage_half(A + (size_t)(bm * 256 + half * 128) * 1024 + kt * 64,
               ldsbuf + buf * 32768 + half * 16384, w, srow, schunk);
  };
  auto stB = [&](int buf, int half, int kt) {
    stage_half(Bt + (size_t)(bn * 256 + half * 128) * 1024 + kt * 64,
               ldsbuf + 65536 + buf * 32768 + half * 16384, w, srow, schunk);
  };

  f32x4 acc[8][4];
  #pragma unroll
  for (int m = 0; m < 8; ++m)
    #pragma unroll
    for (int n = 0; n < 4; ++n)
      acc[m][n] = (f32x4){0.f, 0.f, 0.f, 0.f};

  const int browbase = (wn & 1) * 64;

  stA(0, 0, 0); stA(0, 1, 0); stB(0, 0, 0); stB(0, 1, 0);
  stB(1, 0, 1); stB(1, 1, 1);
  asm volatile("s_waitcnt vmcnt(4)" ::: "memory");
  CBAR(); __builtin_amdgcn_s_barrier(); CBAR();

  bf16x8 bfr[4][2];

  for (int i = 0; i < 8; ++i) {
    const int t1 = 2 * i + 1, t2 = 2 * i + 2, t3 = 2 * i + 3;
    #pragma unroll
    for (int p = 0; p < 8; ++p) {
      const int buf = p >> 2;
      const int q = p & 3;
      const char* aB = ldsbuf + buf * 32768 + wm * 16384;
      const char* bB = ldsbuf + 65536 + buf * 32768 + (wn >> 1) * 16384;
      if (q == 0) {
        #pragma unroll
        for (int n = 0; n < 4; ++n)
          #pragma unroll
          for (int ks = 0; ks < 2; ++ks) {
            int U = (browbase + n * 16 + i16) * 128 + ks * 64 + g * 16;
            bfr[n][ks] = *(const bf16x8*)(bB + (U ^ s5));
          }
      }
      bf16x8 af[2][2];
      #pragma unroll
      for (int mm = 0; mm < 2; ++mm)
        #pragma unroll
        for (int ks = 0; ks < 2; ++ks) {
          int U = ((q * 2 + mm) * 16 + i16) * 128 + ks * 64 + g * 16;
          af[mm][ks] = *(const bf16x8*)(aB + (U ^ s5));
        }
      if (p == 0)      stA(1, 0, t1);
      else if (p == 1) stA(1, 1, t1);
      else if (p == 2) { if (t2 < 16) stB(0, 0, t2); }
      else if (p == 3) { if (t2 < 16) stB(0, 1, t2); }
      else if (p == 4) { if (t2 < 16) stA(0, 0, t2); }
      else if (p == 5) { if (t2 < 16) stA(0, 1, t2); }
      else if (p == 6) { if (t3 < 16) stB(1, 0, t3); }
      else             { if (t3 < 16) stB(1, 1, t3); }

      CBAR(); __builtin_amdgcn_s_barrier(); CBAR();

      __builtin_amdgcn_s_setprio(1);
      #pragma unroll
      for (int mm = 0; mm < 2; ++mm)
        #pragma unroll
        for (int n = 0; n < 4; ++n)
          #pragma unroll
          for (int ks = 0; ks < 2; ++ks)
            acc[q * 2 + mm][n] = __builtin_amdgcn_mfma_f32_16x16x32_bf16(
                af[mm][ks], bfr[n][ks], acc[q * 2 + mm][n], 0, 0, 0);
      __builtin_amdgcn_s_setprio(0);

      if (p == 3) {
        if (i == 7) asm volatile("s_waitcnt vmcnt(0)" ::: "memory");
        else        asm volatile("s_waitcnt vmcnt(4)" ::: "memory");
      } else if (p == 7 && i < 7) {
        asm volatile("s_waitcnt vmcnt(4)" ::: "memory");
      }
      CBAR(); __builtin_amdgcn_s_barrier(); CBAR();
    }
  }

  #pragma unroll
  for (int m = 0; m < 8; ++m) {
    #pragma unroll
    for (int n = 0; n < 4; ++n) {
      int col = bn * 256 + wn * 64 + n * 16 + i16;
      float bv = bias[col];
      int row0 = bm * 256 + wm * 128 + m * 16 + g * 4;
      if (col < 2048) {
        const bool isK = (col >= 1024);
        const float scl = isK ? 0.18033688011112042f : 1.0f;
        bf16_t* base = isK ? kfout : qfout;
        int dg = col & 1023;
        int hh = dg >> 6, d = dg & 63;
        int ks = d >> 4, hib = (d >> 3) & 1, e = d & 7;
        int t = row0 >> 5, l0 = row0 & 31;
        bf16_t* fp = base + (size_t)hh * 262144 + t * 2048 + ks * 512 +
                     hib * 256 + l0 * 8 + e;
        #pragma unroll
        for (int r = 0; r < 4; ++r)
          fp[r * 8] = (bf16_t)((acc[m][n][r] + bv) * scl);
      } else {
        int dg = col - 2048;
        int hh = dg >> 6, dh = dg & 63;
        int dt = dh >> 5, l31v = dh & 31;
        int t = row0 >> 5, inner = row0 & 31;
        int g2 = inner >> 4, hiv = (inner >> 3) & 1, e0 = inner & 7;
        uint2 pk;
        pk.x = cvt_pk_bf16(acc[m][n][0] + bv, acc[m][n][1] + bv);
        pk.y = cvt_pk_bf16(acc[m][n][2] + bv, acc[m][n][3] + bv);
        *(uint2*)(vfout + (size_t)hh * 262144 + t * 2048 + dt * 1024 +
                  g2 * 512 + hiv * 256 + l31v * 8 + e0) = pk;
      }
    }
  }
}

// ---------- GEMM2 (128^2 m97 structure): C = A * Bt^T + bias, fp32 out -----

__global__ __launch_bounds__(256) void gemm_bt(const bf16_t* __restrict__ A,
                                               const bf16_t* __restrict__ Bt,
                                               const float* __restrict__ bias,
                                               float* __restrict__ Cout,
                                               int M, int N, int K) {
  __shared__ bf16_t As[128 * 32];
  __shared__ bf16_t Bs[128 * 32];
  const int tid = threadIdx.x;
  const int lane = tid & 63;
  const int w = tid >> 6;
  const int wr = (w >> 1) * 64;
  const int wc = (w & 1) * 64;
  const int i16 = lane & 15;
  const int g = lane >> 4;
  const int ntn = N >> 7;
  const int nwg = gridDim.x;
  const int bswz = (blockIdx.x & 7) * (nwg >> 3) + (blockIdx.x >> 3);
  const int bm = bswz / ntn;
  const int bn = bswz % ntn;
  const bf16_t* Abase = A + (size_t)(bm * 128) * K;
  const bf16_t* Bbase = Bt + (size_t)(bn * 128) * K;

  f32x4 acc[4][4];
  #pragma unroll
  for (int m = 0; m < 4; ++m)
    #pragma unroll
    for (int n = 0; n < 4; ++n)
      acc[m][n] = (f32x4){0.f, 0.f, 0.f, 0.f};

  for (int kt = 0; kt < K; kt += 32) {
    __syncthreads();
    #pragma unroll
    for (int p = 0; p < 2; ++p) {
      int idx = p * 256 + tid;
      int row = idx >> 2, ch = idx & 3;
      gload_lds16(Abase + (size_t)row * K + kt + ch * 8, (char*)As + idx * 16);
      gload_lds16(Bbase + (size_t)row * K + kt + ch * 8, (char*)Bs + idx * 16);
    }
    __syncthreads();
    bf16x8 af[4], bq[4];
    #pragma unroll
    for (int m = 0; m < 4; ++m)
      af[m] = *(const bf16x8*)(As + (wr + m * 16 + i16) * 32 + g * 8);
    #pragma unroll
    for (int n = 0; n < 4; ++n)
      bq[n] = *(const bf16x8*)(Bs + (wc + n * 16 + i16) * 32 + g * 8);
    #pragma unroll
    for (int m = 0; m < 4; ++m)
      #pragma unroll
      for (int n = 0; n < 4; ++n)
        acc[m][n] = __builtin_amdgcn_mfma_f32_16x16x32_bf16(af[m], bq[n], acc[m][n], 0, 0, 0);
  }

  #pragma unroll
  for (int m = 0; m < 4; ++m) {
    #pragma unroll
    for (int n = 0; n < 4; ++n) {
      int col = bn * 128 + wc + n * 16 + i16;
      float bv = bias ? bias[col] : 0.f;
      int row0 = bm * 128 + wr + m * 16 + g * 4;
      #pragma unroll
      for (int r = 0; r < 4; ++r)
        Cout[(size_t)(row0 + r) * N + col] = acc[m][n][r] + bv;
    }
  }
}

// ---------- causal flash attention: 4-wave KV-split (r16) + permlane pack ---
// Best measured configuration (round 18): fragment-layout direct loads,
// scale-folded shift-free exp2 softmax, K register double-buffer, T12
// permlane32_swap pack, pairwise f32 merge, 18.4KB LDS, VGPR 68.
// S^T = mfma_32x32(K', Q): lane q = lane&31, keys (r&3)+8*(r>>2)+4*(lane>>5).
// O^T = mfma_32x32(V^T, P^T). P = exp2(S') shift-free.

__global__ __launch_bounds__(256) void attn_fwd(const bf16_t* __restrict__ qf_,
                                                const bf16_t* __restrict__ kf,
                                                const bf16_t* __restrict__ vf,
                                                bf16_t* __restrict__ aout) {
  __shared__ float Obuf[2][32][68];
  __shared__ float lpart[4][2][32];
  const int tid = threadIdx.x;
  const int w = tid >> 6;
  const int lane = tid & 63;
  const int l31 = lane & 31;
  const int hi = lane >> 5;
  const int bid = blockIdx.x;
  const int h = ((bid & 7) << 1) | ((bid >> 3) & 1);  // 2 heads per XCD
  const int j = 127 - (bid >> 4);                     // heavy q-tiles first
  const int qg0 = j * 32;

  const bf16_t* qp = qf_ + (size_t)h * 262144 + (size_t)j * 2048 + hi * 256 + l31 * 8;
  bf16x8 qf[4];
  #pragma unroll
  for (int ks = 0; ks < 4; ++ks)
    qf[ks] = *(const bf16x8*)(qp + ks * 512);

  const bf16_t* kp = kf + (size_t)h * 262144 + hi * 256 + l31 * 8;
  const bf16_t* vp = vf + (size_t)h * 262144 + hi * 256 + l31 * 8;

  f32x16 ot0, ot1;
  #pragma unroll
  for (int r = 0; r < 16; ++r) { ot0[r] = 0.f; ot1[r] = 0.f; }
  float l_run = 0.f;

  const int nt = j + 1;
  bf16x8 kc[4], kn[4], vc[4];
  #pragma unroll
  for (int ks = 0; ks < 4; ++ks) {
    kc[ks] = *(const bf16x8*)(kp + w * 2048 + ks * 512);
    kn[ks] = kc[ks];
  }

  for (int t = w; t < nt; t += 4) {
    #pragma unroll
    for (int i = 0; i < 4; ++i) {
      int dt = i >> 1, g2 = i & 1;
      vc[i] = *(const bf16x8*)(vp + (size_t)t * 2048 + dt * 1024 + g2 * 512);
    }
    if (t + 4 < nt) {
      #pragma unroll
      for (int ks = 0; ks < 4; ++ks)
        kn[ks] = *(const bf16x8*)(kp + (size_t)(t + 4) * 2048 + ks * 512);
    }

    f32x16 s;
    #pragma unroll
    for (int r = 0; r < 16; ++r) s[r] = 0.f;
    __builtin_amdgcn_s_setprio(1);
    #pragma unroll
    for (int ks = 0; ks < 4; ++ks)
      s = __builtin_amdgcn_mfma_f32_32x32x16_bf16(kc[ks], qf[ks], s, 0, 0, 0);
    __builtin_amdgcn_s_setprio(0);

    if (t == nt - 1) {
      #pragma unroll
      for (int r = 0; r < 16; ++r) {
        int c = (r & 3) + 8 * (r >> 2) + 4 * hi;
        if (c > l31) s[r] = -1e30f;
      }
    }

    #pragma unroll
    for (int r = 0; r < 16; ++r)
      s[r] = __builtin_amdgcn_exp2f(s[r]);

    float sm[8];
    #pragma unroll
    for (int r = 0; r < 8; ++r) sm[r] = s[r] + s[r + 8];
    #pragma unroll
    for (int r = 0; r < 4; ++r) sm[r] = sm[r] + sm[r + 4];
    l_run += (sm[0] + sm[1]) + (sm[2] + sm[3]);

    // T12 pack: 8 cvt_pk + 4 permlane32_swap (both outputs), zero selects
    bf16x8 pb[2];
    #pragma unroll
    for (int g2 = 0; g2 < 2; ++g2) {
      const int r0 = g2 * 8;
      unsigned a0 = cvt_pk_bf16(s[r0 + 0], s[r0 + 1]);
      unsigned a1 = cvt_pk_bf16(s[r0 + 2], s[r0 + 3]);
      unsigned b0 = cvt_pk_bf16(s[r0 + 4], s[r0 + 5]);
      unsigned b1 = cvt_pk_bf16(s[r0 + 6], s[r0 + 7]);
      uint2e p0 = __builtin_amdgcn_permlane32_swap(a0, b0, false, false);
      uint2e p1 = __builtin_amdgcn_permlane32_swap(a1, b1, false, false);
      uint4 f;
      f.x = p0[0];   // [a0_lo | b0_lo]
      f.y = p1[0];   // [a1_lo | b1_lo]
      f.z = p0[1];   // [a0_hi | b0_hi]
      f.w = p1[1];   // [a1_hi | b1_hi]
      pb[g2] = __builtin_bit_cast(bf16x8, f);
    }

    __builtin_amdgcn_s_setprio(1);
    ot0 = __builtin_amdgcn_mfma_f32_32x32x16_bf16(vc[0], pb[0], ot0, 0, 0, 0);
    ot0 = __builtin_amdgcn_mfma_f32_32x32x16_bf16(vc[1], pb[1], ot0, 0, 0, 0);
    ot1 = __builtin_amdgcn_mfma_f32_32x32x16_bf16(vc[2], pb[0], ot1, 0, 0, 0);
    ot1 = __builtin_amdgcn_mfma_f32_32x32x16_bf16(vc[3], pb[1], ot1, 0, 0, 0);
    __builtin_amdgcn_s_setprio(0);

    #pragma unroll
    for (int ks = 0; ks < 4; ++ks) kc[ks] = kn[ks];
  }

  lpart[w][hi][l31] = l_run;
  if (w >= 2) {
    #pragma unroll
    for (int dt = 0; dt < 2; ++dt) {
      const f32x16& o = dt ? ot1 : ot0;
      #pragma unroll
      for (int rq = 0; rq < 4; ++rq) {
        f32x4 qd;
        qd[0] = o[4 * rq + 0];
        qd[1] = o[4 * rq + 1];
        qd[2] = o[4 * rq + 2];
        qd[3] = o[4 * rq + 3];
        *(f32x4*)&Obuf[w - 2][l31][dt * 32 + 8 * rq + 4 * hi] = qd;
      }
    }
  }
  __syncthreads();
  if (w < 2) {
    #pragma unroll
    for (int dt = 0; dt < 2; ++dt) {
      const f32x16& o = dt ? ot1 : ot0;
      #pragma unroll
      for (int rq = 0; rq < 4; ++rq) {
        f32x4 qd = *(const f32x4*)&Obuf[w][l31][dt * 32 + 8 * rq + 4 * hi];
        qd[0] += o[4 * rq + 0];
        qd[1] += o[4 * rq + 1];
        qd[2] += o[4 * rq + 2];
        qd[3] += o[4 * rq + 3];
        *(f32x4*)&Obuf[w][l31][dt * 32 + 8 * rq + 4 * hi] = qd;
      }
    }
  }
  __syncthreads();
  #pragma unroll
  for (int iter = 0; iter < 8; ++iter) {
    int qq = w * 8 + iter;
    float sum = Obuf[0][qq][lane] + Obuf[1][qq][lane];
    float lst = lpart[0][0][qq] + lpart[0][1][qq] + lpart[1][0][qq] + lpart[1][1][qq] +
                lpart[2][0][qq] + lpart[2][1][qq] + lpart[3][0][qq] + lpart[3][1][qq];
    aout[(size_t)(qg0 + qq) * 1024 + h * 64 + lane] = (bf16_t)(sum / lst);
  }
}

// ---------- launch ----------

extern "C" void kernel_launch(void* const* d_in, const int* in_sizes, int n_in,
                              void* d_out, int out_size, void* d_ws, size_t ws_size,
                              hipStream_t stream) {
  const float* x     = (const float*)d_in[0];
  const float* w_qkv = (const float*)d_in[1];
  const float* b_qkv = (const float*)d_in[2];
  const float* w_o   = (const float*)d_in[3];
  const float* b_o   = (const float*)d_in[4];

  char* ws = (char*)d_ws;
  bf16_t* xh    = (bf16_t*)(ws);                          //  8 MiB
  bf16_t* wqkvT = (bf16_t*)(ws + 8388608);                //  6 MiB
  bf16_t* woT   = (bf16_t*)(ws + 14680064);               //  2 MiB
  bf16_t* qfb   = (bf16_t*)(ws + 16777216);               //  8 MiB  QF fragment layout
  bf16_t* kfb   = (bf16_t*)(ws + 25165824);               //  8 MiB  KF fragment layout
  bf16_t* vfb   = (bf16_t*)(ws + 33554432);               //  8 MiB  VF fragment layout
  bf16_t* aout  = (bf16_t*)(ws + 41943040);               //  8 MiB

  prep_fused<<<5120, 256, 0, stream>>>(x, xh, w_qkv, wqkvT, w_o, woT);

  gemm1_8p<<<192, 512, 0, stream>>>(xh, wqkvT, b_qkv, qfb, kfb, vfb);

  attn_fwd<<<N_HEAD * (SEQ_LEN / 32), 256, 0, stream>>>(qfb, kfb, vfb, aout);

  gemm_bt<<<(4096 / 128) * (1024 / 128), 256, 0, stream>>>(
      aout, woT, b_o, (float*)d_out, 4096, 1024, 1024);
}